// Round 7
// baseline (747.348 us; speedup 1.0000x reference)
//
#include <hip/hip_runtime.h>
#include <hip/hip_bf16.h>

#define B_  4
#define L_  2048      // LO == LQ == 2048
#define H_  128
#define NH_ 2
#define G_  10
#define NIN_ 41

typedef __hip_bfloat16 bf16;
typedef __attribute__((ext_vector_type(8))) short bf16x8s;  // 8 bf16 = 4 VGPRs
typedef __attribute__((ext_vector_type(4))) float f32x4;

__device__ __forceinline__ unsigned short f2bf_bits(float x) {
    __hip_bfloat16 h = __float2bfloat16(x);
    return *reinterpret_cast<unsigned short*>(&h);
}
__device__ __forceinline__ float us2f(unsigned short s) {
    return __uint_as_float(((unsigned int)s) << 16);
}

// ---------------------------------------------------------------------------
// K1: query featurize only -> (B*L, 256) bf16, masked
// ---------------------------------------------------------------------------
__global__ __launch_bounds__(128)
void featq_kernel(const float* __restrict__ xq, const float* __restrict__ mq,
                  const float* __restrict__ w_q0, const float* __restrict__ b_q0,
                  const float* __restrict__ w_q1, const float* __restrict__ b_q1,
                  const float* __restrict__ w_cq, const float* __restrict__ b_cq,
                  bf16* __restrict__ featq)
{
    const int row = blockIdx.x;
    const int j   = threadIdx.x;
    const float t   = xq[row * 2 + 0];
    const float chf = xq[row * 2 + 1];
    int ch = (int)chf; ch = max(0, min(NIN_ - 1, ch));
    const float m   = mq[row];
    float tf;
    if (j == 0) tf = t * w_q0[0] + b_q0[0];
    else        tf = __sinf(t * w_q1[j - 1] + b_q1[j - 1]);
    float cf = fmaxf(w_cq[ch * H_ + j] + b_cq[j], 0.f);
    featq[(size_t)row * 256 + j]       = __float2bfloat16(tf * m);
    featq[(size_t)row * 256 + 128 + j] = __float2bfloat16(cf * m);
}

// ---------------------------------------------------------------------------
// K2: obs featurize only -> (B*L, 288) bf16 (257 real, 31 zero pad), masked
// ---------------------------------------------------------------------------
__global__ __launch_bounds__(128)
void feato_kernel(const float* __restrict__ obs, const float* __restrict__ mobs,
                  const float* __restrict__ w_o0, const float* __restrict__ b_o0,
                  const float* __restrict__ w_o1, const float* __restrict__ b_o1,
                  const float* __restrict__ w_cobs, const float* __restrict__ b_cobs,
                  bf16* __restrict__ feato)
{
    const int row = blockIdx.x;
    const int j   = threadIdx.x;
    const float t   = obs[row * 3 + 0];
    const float chf = obs[row * 3 + 1];
    const float xv  = obs[row * 3 + 2];
    int ch = (int)chf; ch = max(0, min(NIN_ - 1, ch));
    const float m   = mobs[row];
    float tf;
    if (j == 0) tf = t * w_o0[0] + b_o0[0];
    else        tf = __sinf(t * w_o1[j - 1] + b_o1[j - 1]);
    float cf = fmaxf(w_cobs[ch * H_ + j] + b_cobs[j], 0.f);
    bf16* r = feato + (size_t)row * 288;
    r[j]       = __float2bfloat16(tf * m);
    r[128 + j] = __float2bfloat16(cf * m);
    if (j == 0) r[256] = __float2bfloat16(xv * m);
    if (j < 31) r[257 + j] = __float2bfloat16(0.f);
}

// ---------------------------------------------------------------------------
// All weight transposes (fp32 K x N -> bf16 N x Kp, zero pad k>=K) in 1 launch
// ---------------------------------------------------------------------------
struct WtArgs {
    const float* W[8];
    bf16* T[8];
    int K[8], Kp[8], N[8];
};
__global__ __launch_bounds__(288)
void wtrans_all_kernel(WtArgs a)
{
    const int i = blockIdx.y, n = blockIdx.x, k = threadIdx.x;
    if (n >= a.N[i] || k >= a.Kp[i]) return;
    a.T[i][(size_t)n * a.Kp[i] + k] =
        (k < a.K[i]) ? __float2bfloat16(a.W[i][(size_t)k * a.N[i] + n])
                     : __float2bfloat16(0.f);
}

// ---------------------------------------------------------------------------
// KV transpose: in (BH, L, H) -> out (BH, H, L). grid (L/64, BH), 256 thr.
// ---------------------------------------------------------------------------
__global__ __launch_bounds__(256)
void kvtrans_kernel(const bf16* __restrict__ in, bf16* __restrict__ out)
{
    __shared__ unsigned short tile[64 * 136];
    const int tid = threadIdx.x;
    const int l0 = blockIdx.x * 64;
    const int bh = blockIdx.y;
    const unsigned short* src = (const unsigned short*)(in + (size_t)bh * L_ * H_);
    unsigned short* dst = (unsigned short*)(out + (size_t)bh * H_ * L_);
    #pragma unroll
    for (int p = 0; p < 4; p++) {
        const int l = p * 16 + (tid >> 4);
        const int d0 = (tid & 15) * 8;
        *(uint4*)&tile[l * 136 + d0] = *(const uint4*)&src[(size_t)(l0 + l) * H_ + d0];
    }
    __syncthreads();
    const int d  = tid >> 1;
    const int lh = (tid & 1) * 32;
    unsigned short buf[32];
    #pragma unroll
    for (int j = 0; j < 32; j++) buf[j] = tile[(lh + j) * 136 + d];
    #pragma unroll
    for (int j = 0; j < 4; j++)
        *(uint4*)&dst[(size_t)d * L_ + l0 + lh + j * 8] = *(uint4*)&buf[j * 8];
}

// ---------------------------------------------------------------------------
// Generic MFMA GEMM: C = A(bf16 M x K) @ WT(bf16 N x K) + bias(fp32)
// optional bf16 residual R (M x N) added pre-ReLU.
// Block: 128 thr = 2 waves, 32x64 tile. grid (M/32, N/64).
// out modes: 0 fp32 row-major, 1 bf16 row-major, 2 bf16 per-head (B,NH,L,H),
//            3 fp32 split-transposed (B,G,L,H).
// ---------------------------------------------------------------------------
__global__ __launch_bounds__(128)
void gemm_kernel(const bf16* __restrict__ A, const bf16* __restrict__ WT,
                 const float* __restrict__ bias, const bf16* __restrict__ R,
                 void* __restrict__ out, int K, int N, int mode, int do_relu)
{
    const int wave = threadIdx.x >> 6, lane = threadIdx.x & 63;
    const int quad = lane >> 4, l15 = lane & 15;
    const int m0 = blockIdx.x * 32 + wave * 16;
    const int n0 = blockIdx.y * 64;

    f32x4 acc[4];
    #pragma unroll
    for (int c = 0; c < 4; c++) acc[c] = (f32x4){0.f, 0.f, 0.f, 0.f};

    const bf16* arow = A + (size_t)(m0 + l15) * K;
    #pragma unroll 4
    for (int kc = 0; kc < K; kc += 32) {
        bf16x8s af = *(const bf16x8s*)(arow + kc + quad * 8);
        #pragma unroll
        for (int c = 0; c < 4; c++) {
            bf16x8s wf = *(const bf16x8s*)(WT + (size_t)(n0 + c * 16 + l15) * K + kc + quad * 8);
            acc[c] = __builtin_amdgcn_mfma_f32_16x16x32_bf16(af, wf, acc[c], 0, 0, 0);
        }
    }

    #pragma unroll
    for (int c = 0; c < 4; c++) {
        const int n = n0 + c * 16 + l15;
        const float bv = bias[n];
        #pragma unroll
        for (int r = 0; r < 4; r++) {
            const int m = m0 + quad * 4 + r;
            float v = acc[c][r] + bv;
            if (R != nullptr) v += __bfloat162float(R[(size_t)m * N + n]);
            if (do_relu) v = fmaxf(v, 0.f);
            if (mode == 0) {
                ((float*)out)[(size_t)m * N + n] = v;
            } else if (mode == 1) {
                ((bf16*)out)[(size_t)m * N + n] = __float2bfloat16(v);
            } else if (mode == 2) {
                const int b = m >> 11, l = m & 2047, hh = n >> 7, d = n & 127;
                ((bf16*)out)[(((size_t)(b * NH_ + hh)) * L_ + l) * H_ + d] = __float2bfloat16(v);
            } else {
                const int b = m >> 11, q = m & 2047, g = n >> 7, hh = n & 127;
                ((float*)out)[(((size_t)(b * G_ + g)) * L_ + q) * H_ + hh] = v;
            }
        }
    }
}

// ---------------------------------------------------------------------------
// Flash attention v4: 256 thr = 4 waves = 4-way K-split of ONE 16-query tile.
// Q,KV bf16 (BH,L,H); KVT bf16 (BH,H,L); O bf16 (B,L,NH*H). K==V.
// Grid: (BH=8, L/16=128) = 1024 blocks -> 3 blocks/CU, 12 waves/CU.
// Barrier-free K-loop (operands from global/L2, register double-buffered);
// one barrier for the 4-way in-LDS combine.
// ---------------------------------------------------------------------------
#define FTS 40      // Ps row stride (ushorts): 80 B, 16 B-aligned b128 reads

__global__ __launch_bounds__(256, 3)
void flash_attn_kernel(const bf16* __restrict__ Qb, const bf16* __restrict__ KVb,
                       const bf16* __restrict__ KVTb,
                       const float* __restrict__ mQ, const float* __restrict__ mK,
                       bf16* __restrict__ O)
{
    __shared__ __align__(16) char smem[30976];
    unsigned short* Ps = (unsigned short*)smem;             // 4*16*40*2 = 5120 B
    float* Ocomb = (float*)(smem + 5120);                   // 3*16*132*4 = 25344 B
    float* mcomb = (float*)(smem + 5120 + 25344);           // 192 B
    float* lcomb = (float*)(smem + 5120 + 25344 + 192);     // 192 B

    const int tid  = threadIdx.x;
    const int lane = tid & 63;
    const int wave = tid >> 6;        // K-split id 0..3
    const int quad = lane >> 4;
    const int l15  = lane & 15;
    const int bh = blockIdx.x, b = bh >> 1, h = bh & 1;
    const int q0 = blockIdx.y * 16;

    // Q fragments (row-major per-head)
    const bf16* qrow = Qb + ((size_t)bh * L_ + q0 + l15) * H_;
    bf16x8s qf[4];
    #pragma unroll
    for (int kc = 0; kc < 4; kc++)
        qf[kc] = *(const bf16x8s*)(qrow + kc * 32 + quad * 8);

    float qm[4];
    #pragma unroll
    for (int r = 0; r < 4; r++)
        qm[r] = (mQ == nullptr) ? 1.f : mQ[b * L_ + q0 + quad * 4 + r];

    float mo[4], li[4];
    f32x4 Oacc[8];
    #pragma unroll
    for (int r = 0; r < 4; r++) { mo[r] = -1e30f; li[r] = 0.f; }
    #pragma unroll
    for (int c = 0; c < 8; c++) Oacc[c] = (f32x4){0.f, 0.f, 0.f, 0.f};

    const float SCALE = 0.08838834764831845f;    // 1/sqrt(128)
    const bf16* kvb = KVb  + (size_t)bh * L_ * H_;
    const bf16* kvt = KVTb + (size_t)bh * H_ * L_;
    const float* mkb = mK + b * L_;
    unsigned short* pw = Ps + wave * 16 * FTS;

    const int ks0 = wave * 512;                  // this wave's key range
    bf16x8s kf[2][8];
    float km[2][2];
    #pragma unroll
    for (int kc = 0; kc < 4; kc++) {
        kf[0][kc]     = *(const bf16x8s*)(kvb + (size_t)(ks0 + l15) * H_ + kc * 32 + quad * 8);
        kf[0][4 + kc] = *(const bf16x8s*)(kvb + (size_t)(ks0 + 16 + l15) * H_ + kc * 32 + quad * 8);
    }
    km[0][0] = mkb[ks0 + l15];
    km[0][1] = mkb[ks0 + 16 + l15];

    for (int it = 0; it < 16; it++) {
        const int cur = it & 1;
        const int kbase = ks0 + it * 32;

        // ---- V^T fragments for this tile (latency hides under softmax) ----
        bf16x8s vf[8];
        #pragma unroll
        for (int c = 0; c < 8; c++)
            vf[c] = *(const bf16x8s*)(kvt + (size_t)(c * 16 + l15) * L_ + kbase + quad * 8);

        // ---- S = Q K^T ----
        f32x4 s0a = (f32x4){0.f,0.f,0.f,0.f}, s1a = (f32x4){0.f,0.f,0.f,0.f};
        #pragma unroll
        for (int kc = 0; kc < 4; kc++) {
            s0a = __builtin_amdgcn_mfma_f32_16x16x32_bf16(qf[kc], kf[cur][kc],     s0a, 0, 0, 0);
            s1a = __builtin_amdgcn_mfma_f32_16x16x32_bf16(qf[kc], kf[cur][4 + kc], s1a, 0, 0, 0);
        }

        // ---- prefetch next K tile + mask ----
        if (it < 15) {
            const int kn = kbase + 32;
            #pragma unroll
            for (int kc = 0; kc < 4; kc++) {
                kf[cur ^ 1][kc]     = *(const bf16x8s*)(kvb + (size_t)(kn + l15) * H_ + kc * 32 + quad * 8);
                kf[cur ^ 1][4 + kc] = *(const bf16x8s*)(kvb + (size_t)(kn + 16 + l15) * H_ + kc * 32 + quad * 8);
            }
            km[cur ^ 1][0] = mkb[kn + l15];
            km[cur ^ 1][1] = mkb[kn + 16 + l15];
        }

        // ---- mask + online softmax ----
        const float km0 = km[cur][0];
        const float km1 = km[cur][1];
        float s0[4], s1[4], mx[4];
        #pragma unroll
        for (int r = 0; r < 4; r++) {
            s0[r] = (km0 != 0.f && qm[r] != 0.f) ? s0a[r] * SCALE : -1000000.f;
            s1[r] = (km1 != 0.f && qm[r] != 0.f) ? s1a[r] * SCALE : -1000000.f;
            mx[r] = fmaxf(s0[r], s1[r]);
        }
        #pragma unroll
        for (int off = 1; off < 16; off <<= 1)
            #pragma unroll
            for (int r = 0; r < 4; r++) mx[r] = fmaxf(mx[r], __shfl_xor(mx[r], off));

        float p0[4], p1[4], rs[4], al[4];
        #pragma unroll
        for (int r = 0; r < 4; r++) {
            const float mn = fmaxf(mo[r], mx[r]);
            al[r] = __expf(mo[r] - mn);
            mo[r] = mn;
            p0[r] = __expf(s0[r] - mn);
            p1[r] = __expf(s1[r] - mn);
            rs[r] = p0[r] + p1[r];
        }
        #pragma unroll
        for (int off = 1; off < 16; off <<= 1)
            #pragma unroll
            for (int r = 0; r < 4; r++) rs[r] += __shfl_xor(rs[r], off);
        #pragma unroll
        for (int r = 0; r < 4; r++) li[r] = li[r] * al[r] + rs[r];
        #pragma unroll
        for (int c = 0; c < 8; c++)
            #pragma unroll
            for (int r = 0; r < 4; r++) Oacc[c][r] *= al[r];

        // ---- P -> LDS (wave-private, no barrier) -> A-frag ----
        #pragma unroll
        for (int r = 0; r < 4; r++) {
            pw[(quad * 4 + r) * FTS + l15]      = f2bf_bits(p0[r]);
            pw[(quad * 4 + r) * FTS + 16 + l15] = f2bf_bits(p1[r]);
        }
        bf16x8s pf = *(bf16x8s*)(&pw[l15 * FTS + quad * 8]);

        // ---- O += P V ----
        #pragma unroll
        for (int c = 0; c < 8; c++)
            Oacc[c] = __builtin_amdgcn_mfma_f32_16x16x32_bf16(pf, vf[c], Oacc[c], 0, 0, 0);
    }

    // ---- 4-way K-split combine ----
    if (wave > 0) {
        const int s = wave - 1;
        #pragma unroll
        for (int c = 0; c < 8; c++)
            #pragma unroll
            for (int r = 0; r < 4; r++)
                Ocomb[(size_t)(s * 16 + quad * 4 + r) * 132 + c * 16 + l15] = Oacc[c][r];
        if (l15 == 0) {
            #pragma unroll
            for (int r = 0; r < 4; r++) {
                mcomb[s * 16 + quad * 4 + r] = mo[r];
                lcomb[s * 16 + quad * 4 + r] = li[r];
            }
        }
    }
    __syncthreads();
    if (wave == 0) {
        float ms[3][4], ls[3][4], M[4];
        #pragma unroll
        for (int r = 0; r < 4; r++) M[r] = mo[r];
        #pragma unroll
        for (int s = 0; s < 3; s++)
            #pragma unroll
            for (int r = 0; r < 4; r++) {
                ms[s][r] = mcomb[s * 16 + quad * 4 + r];
                ls[s][r] = lcomb[s * 16 + quad * 4 + r];
                M[r] = fmaxf(M[r], ms[s][r]);
            }
        float a0[4];
        #pragma unroll
        for (int r = 0; r < 4; r++) {
            a0[r] = __expf(mo[r] - M[r]);
            li[r] *= a0[r];
        }
        #pragma unroll
        for (int c = 0; c < 8; c++)
            #pragma unroll
            for (int r = 0; r < 4; r++) Oacc[c][r] *= a0[r];
        #pragma unroll
        for (int s = 0; s < 3; s++) {
            float as[4];
            #pragma unroll
            for (int r = 0; r < 4; r++) {
                as[r] = __expf(ms[s][r] - M[r]);
                li[r] += as[r] * ls[s][r];
            }
            #pragma unroll
            for (int c = 0; c < 8; c++)
                #pragma unroll
                for (int r = 0; r < 4; r++)
                    Oacc[c][r] += as[r] *
                        Ocomb[(size_t)(s * 16 + quad * 4 + r) * 132 + c * 16 + l15];
        }
        bf16* orow = O + ((size_t)b * L_ + q0) * (NH_ * H_) + h * H_;
        #pragma unroll
        for (int r = 0; r < 4; r++) {
            const float inv = 1.f / li[r];
            #pragma unroll
            for (int c = 0; c < 8; c++)
                orow[(size_t)(quad * 4 + r) * (NH_ * H_) + c * 16 + l15] =
                    __float2bfloat16(Oacc[c][r] * inv);
        }
    }
}

// ---------------------------------------------------------------------------
// qmw builder: mix_wt(10x128) @ ww_q(128x256) + b -> bf16 per-head (2,16,128)
// ---------------------------------------------------------------------------
__global__ __launch_bounds__(256)
void qmwb_kernel(const float* __restrict__ mixwt, const float* __restrict__ W,
                 const float* __restrict__ bias, bf16* __restrict__ qmwb)
{
    const int g = blockIdx.x;          // 0..15
    const int c = threadIdx.x;         // 0..255
    const int h = c >> 7, d = c & 127;
    if (g >= G_) { qmwb[((size_t)h * 16 + g) * 128 + d] = __float2bfloat16(0.f); return; }
    __shared__ float xr[128];
    if (c < 128) xr[c] = mixwt[g * 128 + c];
    __syncthreads();
    float acc = bias[c];
    #pragma unroll 8
    for (int i = 0; i < 128; i++)
        acc += xr[i] * W[i * 256 + c];
    qmwb[((size_t)h * 16 + g) * 128 + d] = __float2bfloat16(acc);
}

// ---------------------------------------------------------------------------
// mw partial attention: 16-way K-split. grid (16, NH, B), 256 threads.
// ---------------------------------------------------------------------------
__global__ __launch_bounds__(256)
void mwpartial_kernel(const bf16* __restrict__ qmwb, const bf16* __restrict__ kvmw,
                      const float* __restrict__ mK,
                      float* __restrict__ mwO, float* __restrict__ mwM,
                      float* __restrict__ mwL)
{
    __shared__ __align__(16) unsigned short Ks[128 * 136];
    __shared__ float Qs[10 * 128];
    __shared__ float sc[10 * 128];
    __shared__ float mst[10], lst[10];

    const int tid = threadIdx.x;
    const int split = blockIdx.x, h = blockIdx.y, b = blockIdx.z;
    const int kbase = split * 128;
    const float SCALE = 0.08838834764831845f;

    for (int idx = tid; idx < 1280; idx += 256)
        Qs[idx] = __bfloat162float(qmwb[((size_t)h * 16 + (idx >> 7)) * 128 + (idx & 127)]);
    {
        const int rr = tid >> 1, half = tid & 1;
        const bf16* src = kvmw + (((size_t)(b * NH_ + h)) * L_ + kbase + rr) * H_ + half * 64;
        #pragma unroll
        for (int i = 0; i < 8; i++)
            *(uint4*)(&Ks[rr * 136 + half * 64 + i * 8]) = *(const uint4*)(src + i * 8);
    }
    __syncthreads();

    {
        const int j = tid & 127, qh = tid >> 7;
        float acc[5] = {0.f, 0.f, 0.f, 0.f, 0.f};
        for (int dc = 0; dc < 128; dc += 8) {
            bf16x8s kv = *(bf16x8s*)(&Ks[j * 136 + dc]);
            float kf[8];
            #pragma unroll
            for (int e = 0; e < 8; e++) kf[e] = us2f(((unsigned short*)&kv)[e]);
            #pragma unroll
            for (int qq = 0; qq < 5; qq++) {
                const float* Qrow = &Qs[(qh * 5 + qq) * 128 + dc];
                #pragma unroll
                for (int e = 0; e < 8; e++) acc[qq] += Qrow[e] * kf[e];
            }
        }
        const bool kz = (mK[b * L_ + kbase + j] == 0.f);
        #pragma unroll
        for (int qq = 0; qq < 5; qq++)
            sc[(qh * 5 + qq) * 128 + j] = kz ? -1000000.f : acc[qq] * SCALE;
    }
    __syncthreads();
    if (tid < 160) {
        const int q = tid >> 4, t16 = tid & 15;
        float m = -3.4e38f;
        for (int jj = t16; jj < 128; jj += 16) m = fmaxf(m, sc[q * 128 + jj]);
        #pragma unroll
        for (int off = 1; off < 16; off <<= 1) m = fmaxf(m, __shfl_xor(m, off));
        if (t16 == 0) mst[q] = m;
    }
    __syncthreads();
    {
        const int j = tid & 127, qh = tid >> 7;
        #pragma unroll
        for (int qq = 0; qq < 5; qq++) {
            const int idx = (qh * 5 + qq) * 128 + j;
            sc[idx] = __expf(sc[idx] - mst[qh * 5 + qq]);
        }
    }
    __syncthreads();
    if (tid < 160) {
        const int q = tid >> 4, t16 = tid & 15;
        float s = 0.f;
        for (int jj = t16; jj < 128; jj += 16) s += sc[q * 128 + jj];
        #pragma unroll
        for (int off = 1; off < 16; off <<= 1) s += __shfl_xor(s, off);
        if (t16 == 0) lst[q] = s;
    }
    __syncthreads();
    {
        const int d = tid & 127, qh = tid >> 7;
        float acc[5] = {0.f, 0.f, 0.f, 0.f, 0.f};
        for (int jj = 0; jj < 128; jj++) {
            const float v = us2f(Ks[jj * 136 + d]);
            #pragma unroll
            for (int qq = 0; qq < 5; qq++)
                acc[qq] += sc[(qh * 5 + qq) * 128 + jj] * v;
        }
        const size_t base = ((size_t)(b * NH_ + h) * 16 + split) * 10;
        #pragma unroll
        for (int qq = 0; qq < 5; qq++)
            mwO[(base + qh * 5 + qq) * 128 + d] = acc[qq];
    }
    if (tid < 10) {
        const size_t base = ((size_t)(b * NH_ + h) * 16 + split) * 10;
        mwM[base + tid] = mst[tid];
        mwL[base + tid] = lst[tid];
    }
}

// mw combine: merge 16 K-splits -> mwat (B*10, 256) fp32. grid 40 x 256
__global__ __launch_bounds__(256)
void mwcombine_kernel(const float* __restrict__ mwO, const float* __restrict__ mwM,
                      const float* __restrict__ mwL, float* __restrict__ mwat)
{
    const int bg = blockIdx.x;
    const int b = bg / G_, q = bg % G_;
    const int h = threadIdx.x >> 7, d = threadIdx.x & 127;
    const size_t hb = (size_t)(b * NH_ + h) * 16;
    float M = -3.4e38f;
    for (int s = 0; s < 16; s++) M = fmaxf(M, mwM[(hb + s) * 10 + q]);
    float l = 0.f, o = 0.f;
    for (int s = 0; s < 16; s++) {
        const float a = __expf(mwM[(hb + s) * 10 + q] - M);
        l += a * mwL[(hb + s) * 10 + q];
        o += a * mwO[((hb + s) * 10 + q) * 128 + d];
    }
    mwat[(size_t)bg * 256 + h * 128 + d] = o / l;
}

// mw output projection: mw_ = mix_wt[g] + attn@ww_o + ww_ob ; grid B*G x 128
__global__ __launch_bounds__(128)
void mwproj_kernel(const float* __restrict__ A, const float* __restrict__ mixwt,
                   const float* __restrict__ W, const float* __restrict__ bias,
                   float* __restrict__ Y)
{
    const int bg  = blockIdx.x;
    const int g   = bg % G_;
    const int tid = threadIdx.x;
    __shared__ float ar[256];
    ar[tid]       = A[(size_t)bg * 256 + tid];
    ar[tid + 128] = A[(size_t)bg * 256 + tid + 128];
    __syncthreads();
    float acc = mixwt[g * 128 + tid] + bias[tid];
    #pragma unroll 8
    for (int i = 0; i < 256; i++)
        acc += ar[i] * W[i * 128 + tid];
    Y[(size_t)bg * 128 + tid] = acc;
}

__global__ __launch_bounds__(64)
void mwfinal_kernel(const float* __restrict__ MW, const float* __restrict__ wmix,
                    const float* __restrict__ bmix, float* __restrict__ out)
{
    const int b = blockIdx.x;
    const int g = threadIdx.x;
    __shared__ float z[16];
    if (g < G_) {
        float acc = bmix[0];
        for (int i = 0; i < 128; i++)
            acc += MW[((size_t)b * G_ + g) * 128 + i] * wmix[i];
        z[g] = acc;
    }
    __syncthreads();
    if (g == 0) {
        float mx = -3.4e38f;
        for (int i = 0; i < G_; i++) mx = fmaxf(mx, z[i]);
        float e[G_]; float s = 0.f;
        for (int i = 0; i < G_; i++) { e[i] = __expf(z[i] - mx); s += e[i]; }
        for (int i = 0; i < G_; i++) out[b * G_ + i] = e[i] / s;
    }
}

// ---------------------------------------------------------------------------
extern "C" void kernel_launch(void* const* d_in, const int* in_sizes, int n_in,
                              void* d_out, int out_size, void* d_ws, size_t ws_size,
                              hipStream_t stream)
{
    const float* obs    = (const float*)d_in[0];
    const float* mobs   = (const float*)d_in[1];
    const float* xq     = (const float*)d_in[2];
    const float* mq     = (const float*)d_in[3];
    const float* w_q0   = (const float*)d_in[4];
    const float* b_q0   = (const float*)d_in[5];
    const float* w_q1   = (const float*)d_in[6];
    const float* b_q1   = (const float*)d_in[7];
    const float* w_o0   = (const float*)d_in[8];
    const float* b_o0   = (const float*)d_in[9];
    const float* w_o1   = (const float*)d_in[10];
    const float* b_o1   = (const float*)d_in[11];
    const float* w_cobs = (const float*)d_in[12];
    const float* b_cobs = (const float*)d_in[13];
    const float* w_cq   = (const float*)d_in[14];
    const float* b_cq   = (const float*)d_in[15];
    const float* w_qp   = (const float*)d_in[16];
    const float* b_qp   = (const float*)d_in[17];
    const float* w_kp   = (const float*)d_in[18];
    const float* b_kp   = (const float*)d_in[19];
    const float* ws_q   = (const float*)d_in[20];
    const float* ws_qb  = (const float*)d_in[21];
    const float* ws_o   = (const float*)d_in[22];
    const float* ws_ob  = (const float*)d_in[23];
    const float* ww_q   = (const float*)d_in[24];
    const float* ww_qb  = (const float*)d_in[25];
    const float* ww_o   = (const float*)d_in[26];
    const float* ww_ob  = (const float*)d_in[27];
    const float* wc_q   = (const float*)d_in[28];
    const float* wc_qb  = (const float*)d_in[29];
    const float* wc_o   = (const float*)d_in[30];
    const float* wc_ob  = (const float*)d_in[31];
    const float* w_split= (const float*)d_in[32];
    const float* b_split= (const float*)d_in[33];
    const float* mix_wt = (const float*)d_in[34];
    const float* w_mix  = (const float*)d_in[35];
    const float* b_mix  = (const float*)d_in[36];

    float* out = (float*)d_out;
    char* ws  = (char*)d_ws;

    const size_t MB = (size_t)1 << 20;
    const size_t KB = (size_t)1 << 10;
    if (ws_size < 31 * MB) return;

    const int NROW = B_ * L_;          // 8192
    // layout (<=30 MB). qcb+kvcb and qe_bf+x_bf pairs MUST be contiguous.
    bf16* featq = (bf16*)(ws + 0);                 // 4 MB  -> kvbs, later qcb
    bf16* feato = (bf16*)(ws + 4 * MB);            // 4.5 MB -> later kvcb (at +4MB!)
    bf16* qe_bf = (bf16*)(ws + 8 * MB + 512 * KB); // 2 MB  \ contiguous pair
    bf16* x_bf  = (bf16*)(ws + 10 * MB + 512 * KB);// 2 MB  / for merged gemm
    bf16* oe_bf = (bf16*)(ws + 12 * MB + 512 * KB);// 2 MB
    bf16* abuf  = (bf16*)(ws + 14 * MB + 512 * KB);// 4 MB -> abuf2
    bf16* x2_bf = (bf16*)(ws + 18 * MB + 512 * KB);// 2 MB
    bf16* kvmw  = (bf16*)(ws + 20 * MB + 512 * KB);// 4 MB
    bf16* kvT   = (bf16*)(ws + 24 * MB + 512 * KB);// 4 MB (BH,H,L), self then cross
    char* wbase = ws + 28 * MB + 512 * KB;         // ~1.5 MB of weights/smalls
    bf16* wqpT  = (bf16*)(wbase + 0);              // 64 KB (128 x 256)
    bf16* wkpT  = (bf16*)(wbase + 64 * KB);        // 72 KB (128 x 288)
    bf16* wsqT  = (bf16*)(wbase + 136 * KB);       // 64 KB (256 x 128)
    bf16* wsoT  = (bf16*)(wbase + 200 * KB);       // 64 KB (128 x 256)
    bf16* wwqT  = (bf16*)(wbase + 264 * KB);       // 64 KB
    bf16* wcqT  = (bf16*)(wbase + 328 * KB);       // 64 KB
    bf16* wcoT  = (bf16*)(wbase + 392 * KB);       // 64 KB
    bf16* wsplT = (bf16*)(wbase + 456 * KB);       // 320 KB (1280 x 128)
    bf16* qmwb  = (bf16*)(wbase + 776 * KB);       // 8 KB (2,16,128)
    float* mwO  = (float*)(wbase + 784 * KB);      // 640 KB
    float* mwM  = (float*)(wbase + 1424 * KB);     // 5 KB
    float* mwL  = (float*)(wbase + 1432 * KB);     // 5 KB
    float* mwat = (float*)(wbase + 1440 * KB);     // 40 KB
    float* mw_  = (float*)(wbase + 1480 * KB);     // 20 KB
    bf16* kvbs  = featq;                           // self QKV (B,NH,L,H)
    bf16* qcb   = featq;                           // cross Q  (B,NH,L,H)
    bf16* kvcb  = (bf16*)(ws + 4 * MB);            // cross KV = qcb + 4MB
    bf16* abuf2 = abuf;

    // 0: all weight transposes in one launch
    WtArgs wa;
    wa.W[0]=w_qp;   wa.T[0]=wqpT;  wa.K[0]=256; wa.Kp[0]=256; wa.N[0]=128;
    wa.W[1]=w_kp;   wa.T[1]=wkpT;  wa.K[1]=257; wa.Kp[1]=288; wa.N[1]=128;
    wa.W[2]=ws_q;   wa.T[2]=wsqT;  wa.K[2]=128; wa.Kp[2]=128; wa.N[2]=256;
    wa.W[3]=ws_o;   wa.T[3]=wsoT;  wa.K[3]=256; wa.Kp[3]=256; wa.N[3]=128;
    wa.W[4]=ww_q;   wa.T[4]=wwqT;  wa.K[4]=128; wa.Kp[4]=128; wa.N[4]=256;
    wa.W[5]=wc_q;   wa.T[5]=wcqT;  wa.K[5]=128; wa.Kp[5]=128; wa.N[5]=256;
    wa.W[6]=wc_o;   wa.T[6]=wcoT;  wa.K[6]=256; wa.Kp[6]=256; wa.N[6]=128;
    wa.W[7]=w_split;wa.T[7]=wsplT; wa.K[7]=128; wa.Kp[7]=128; wa.N[7]=1280;
    wtrans_all_kernel<<<dim3(1280, 8), 288, 0, stream>>>(wa);

    // 1-2: featurize
    featq_kernel<<<NROW, 128, 0, stream>>>(xq, mq, w_q0, b_q0, w_q1, b_q1,
                                           w_cq, b_cq, featq);
    feato_kernel<<<NROW, 128, 0, stream>>>(obs, mobs, w_o0, b_o0, w_o1, b_o1,
                                           w_cobs, b_cobs, feato);
    // 3-4: embed projections (MFMA)
    gemm_kernel<<<dim3(NROW/32, 2), 128, 0, stream>>>(featq, wqpT, b_qp, nullptr,
                                                      qe_bf, 256, 128, 1, 0);
    gemm_kernel<<<dim3(NROW/32, 2), 128, 0, stream>>>(feato, wkpT, b_kp, nullptr,
                                                      oe_bf, 288, 128, 1, 0);
    // 5: self-attn shared q=k=v projection (per-head bf16) + transpose
    gemm_kernel<<<dim3(NROW/32, 4), 128, 0, stream>>>(oe_bf, wsqT, ws_qb, nullptr,
                                                      kvbs, 128, 256, 2, 0);
    kvtrans_kernel<<<dim3(L_/64, B_*NH_), 256, 0, stream>>>(kvbs, kvT);
    // 6: self attention (flash v4)
    flash_attn_kernel<<<dim3(B_*NH_, L_/16), 256, 0, stream>>>(kvbs, kvbs, kvT,
                                                               nullptr, mobs, abuf);
    // 7: x = relu(oe + attn @ ws_o + ws_ob)
    gemm_kernel<<<dim3(NROW/32, 2), 128, 0, stream>>>(abuf, wsoT, ws_ob, oe_bf,
                                                      x_bf, 256, 128, 1, 1);
    // 8-13: mixing-weights path
    qmwb_kernel<<<16, 256, 0, stream>>>(mix_wt, ww_q, ww_qb, qmwb);
    gemm_kernel<<<dim3(NROW/32, 4), 128, 0, stream>>>(x_bf, wwqT, ww_qb, nullptr,
                                                      kvmw, 128, 256, 2, 0);
    mwpartial_kernel<<<dim3(16, NH_, B_), 256, 0, stream>>>(qmwb, kvmw, mobs,
                                                            mwO, mwM, mwL);
    mwcombine_kernel<<<B_ * G_, 256, 0, stream>>>(mwO, mwM, mwL, mwat);
    mwproj_kernel<<<B_ * G_, 128, 0, stream>>>(mwat, mix_wt, ww_o, ww_ob, mw_);
    mwfinal_kernel<<<B_, 64, 0, stream>>>(mw_, w_mix, b_mix,
                                          out + (size_t)B_ * G_ * L_ * H_);
    // 14: merged cross projections: [qe_bf; x_bf](16384x128) @ wc_q -> [qcb; kvcb]
    gemm_kernel<<<dim3(2*NROW/32, 4), 128, 0, stream>>>(qe_bf, wcqT, wc_qb, nullptr,
                                                        qcb, 128, 256, 2, 0);
    kvtrans_kernel<<<dim3(L_/64, B_*NH_), 256, 0, stream>>>(kvcb, kvT);
    // 16: cross attention
    flash_attn_kernel<<<dim3(B_*NH_, L_/16), 256, 0, stream>>>(qcb, kvcb, kvT,
                                                               mq, mobs, abuf2);
    // 17: x2 = relu(qe + attn2 @ wc_o + wc_ob)
    gemm_kernel<<<dim3(NROW/32, 2), 128, 0, stream>>>(abuf2, wcoT, wc_ob, qe_bf,
                                                      x2_bf, 256, 128, 1, 1);
    // 18: split + transpose store (MFMA)
    gemm_kernel<<<dim3(NROW/32, 20), 128, 0, stream>>>(x2_bf, wsplT, b_split, nullptr,
                                                       out, 128, 1280, 3, 0);

    (void)in_sizes; (void)n_in; (void)out_size;
}

// Round 8
// 554.688 us; speedup vs baseline: 1.3473x; 1.3473x over previous
//
#include <hip/hip_runtime.h>
#include <hip/hip_bf16.h>

#define B_  4
#define L_  2048      // LO == LQ == 2048
#define H_  128
#define NH_ 2
#define G_  10
#define NIN_ 41

typedef __hip_bfloat16 bf16;
typedef __attribute__((ext_vector_type(8))) short bf16x8s;  // 8 bf16 = 4 VGPRs
typedef __attribute__((ext_vector_type(4))) float f32x4;

__device__ __forceinline__ unsigned short f2bf_bits(float x) {
    __hip_bfloat16 h = __float2bfloat16(x);
    return *reinterpret_cast<unsigned short*>(&h);
}
__device__ __forceinline__ float us2f(unsigned short s) {
    return __uint_as_float(((unsigned int)s) << 16);
}

// ---------------------------------------------------------------------------
// K1: query featurize only -> (B*L, 256) bf16, masked
// ---------------------------------------------------------------------------
__global__ __launch_bounds__(128)
void featq_kernel(const float* __restrict__ xq, const float* __restrict__ mq,
                  const float* __restrict__ w_q0, const float* __restrict__ b_q0,
                  const float* __restrict__ w_q1, const float* __restrict__ b_q1,
                  const float* __restrict__ w_cq, const float* __restrict__ b_cq,
                  bf16* __restrict__ featq)
{
    const int row = blockIdx.x;
    const int j   = threadIdx.x;
    const float t   = xq[row * 2 + 0];
    const float chf = xq[row * 2 + 1];
    int ch = (int)chf; ch = max(0, min(NIN_ - 1, ch));
    const float m   = mq[row];
    float tf;
    if (j == 0) tf = t * w_q0[0] + b_q0[0];
    else        tf = __sinf(t * w_q1[j - 1] + b_q1[j - 1]);
    float cf = fmaxf(w_cq[ch * H_ + j] + b_cq[j], 0.f);
    featq[(size_t)row * 256 + j]       = __float2bfloat16(tf * m);
    featq[(size_t)row * 256 + 128 + j] = __float2bfloat16(cf * m);
}

// ---------------------------------------------------------------------------
// K2: obs featurize only -> (B*L, 288) bf16 (257 real, 31 zero pad), masked
// ---------------------------------------------------------------------------
__global__ __launch_bounds__(128)
void feato_kernel(const float* __restrict__ obs, const float* __restrict__ mobs,
                  const float* __restrict__ w_o0, const float* __restrict__ b_o0,
                  const float* __restrict__ w_o1, const float* __restrict__ b_o1,
                  const float* __restrict__ w_cobs, const float* __restrict__ b_cobs,
                  bf16* __restrict__ feato)
{
    const int row = blockIdx.x;
    const int j   = threadIdx.x;
    const float t   = obs[row * 3 + 0];
    const float chf = obs[row * 3 + 1];
    const float xv  = obs[row * 3 + 2];
    int ch = (int)chf; ch = max(0, min(NIN_ - 1, ch));
    const float m   = mobs[row];
    float tf;
    if (j == 0) tf = t * w_o0[0] + b_o0[0];
    else        tf = __sinf(t * w_o1[j - 1] + b_o1[j - 1]);
    float cf = fmaxf(w_cobs[ch * H_ + j] + b_cobs[j], 0.f);
    bf16* r = feato + (size_t)row * 288;
    r[j]       = __float2bfloat16(tf * m);
    r[128 + j] = __float2bfloat16(cf * m);
    if (j == 0) r[256] = __float2bfloat16(xv * m);
    if (j < 31) r[257 + j] = __float2bfloat16(0.f);
}

// ---------------------------------------------------------------------------
// All weight transposes (fp32 K x N -> bf16 N x Kp, zero pad k>=K) in 1 launch
// ---------------------------------------------------------------------------
struct WtArgs {
    const float* W[8];
    bf16* T[8];
    int K[8], Kp[8], N[8];
};
__global__ __launch_bounds__(288)
void wtrans_all_kernel(WtArgs a)
{
    const int i = blockIdx.y, n = blockIdx.x, k = threadIdx.x;
    if (n >= a.N[i] || k >= a.Kp[i]) return;
    a.T[i][(size_t)n * a.Kp[i] + k] =
        (k < a.K[i]) ? __float2bfloat16(a.W[i][(size_t)k * a.N[i] + n])
                     : __float2bfloat16(0.f);
}

// ---------------------------------------------------------------------------
// KV transpose: in (BH, L, H) -> out (BH, H, L). grid (L/64, BH), 256 thr.
// ---------------------------------------------------------------------------
__global__ __launch_bounds__(256)
void kvtrans_kernel(const bf16* __restrict__ in, bf16* __restrict__ out)
{
    __shared__ unsigned short tile[64 * 136];
    const int tid = threadIdx.x;
    const int l0 = blockIdx.x * 64;
    const int bh = blockIdx.y;
    const unsigned short* src = (const unsigned short*)(in + (size_t)bh * L_ * H_);
    unsigned short* dst = (unsigned short*)(out + (size_t)bh * H_ * L_);
    #pragma unroll
    for (int p = 0; p < 4; p++) {
        const int l = p * 16 + (tid >> 4);
        const int d0 = (tid & 15) * 8;
        *(uint4*)&tile[l * 136 + d0] = *(const uint4*)&src[(size_t)(l0 + l) * H_ + d0];
    }
    __syncthreads();
    const int d  = tid >> 1;
    const int lh = (tid & 1) * 32;
    unsigned short buf[32];
    #pragma unroll
    for (int j = 0; j < 32; j++) buf[j] = tile[(lh + j) * 136 + d];
    #pragma unroll
    for (int j = 0; j < 4; j++)
        *(uint4*)&dst[(size_t)d * L_ + l0 + lh + j * 8] = *(uint4*)&buf[j * 8];
}

// ---------------------------------------------------------------------------
// Generic MFMA GEMM: C = A(bf16 M x K) @ WT(bf16 N x K) + bias(fp32)
// optional bf16 residual R (M x N) added pre-ReLU.
// Block: 128 thr = 2 waves, 32x64 tile. grid (M/32, N/64).
// out modes: 0 fp32 row-major, 1 bf16 row-major, 2 bf16 per-head (B,NH,L,H),
//            3 fp32 split-transposed (B,G,L,H).
// ---------------------------------------------------------------------------
__global__ __launch_bounds__(128)
void gemm_kernel(const bf16* __restrict__ A, const bf16* __restrict__ WT,
                 const float* __restrict__ bias, const bf16* __restrict__ R,
                 void* __restrict__ out, int K, int N, int mode, int do_relu)
{
    const int wave = threadIdx.x >> 6, lane = threadIdx.x & 63;
    const int quad = lane >> 4, l15 = lane & 15;
    const int m0 = blockIdx.x * 32 + wave * 16;
    const int n0 = blockIdx.y * 64;

    f32x4 acc[4];
    #pragma unroll
    for (int c = 0; c < 4; c++) acc[c] = (f32x4){0.f, 0.f, 0.f, 0.f};

    const bf16* arow = A + (size_t)(m0 + l15) * K;
    #pragma unroll 4
    for (int kc = 0; kc < K; kc += 32) {
        bf16x8s af = *(const bf16x8s*)(arow + kc + quad * 8);
        #pragma unroll
        for (int c = 0; c < 4; c++) {
            bf16x8s wf = *(const bf16x8s*)(WT + (size_t)(n0 + c * 16 + l15) * K + kc + quad * 8);
            acc[c] = __builtin_amdgcn_mfma_f32_16x16x32_bf16(af, wf, acc[c], 0, 0, 0);
        }
    }

    #pragma unroll
    for (int c = 0; c < 4; c++) {
        const int n = n0 + c * 16 + l15;
        const float bv = bias[n];
        #pragma unroll
        for (int r = 0; r < 4; r++) {
            const int m = m0 + quad * 4 + r;
            float v = acc[c][r] + bv;
            if (R != nullptr) v += __bfloat162float(R[(size_t)m * N + n]);
            if (do_relu) v = fmaxf(v, 0.f);
            if (mode == 0) {
                ((float*)out)[(size_t)m * N + n] = v;
            } else if (mode == 1) {
                ((bf16*)out)[(size_t)m * N + n] = __float2bfloat16(v);
            } else if (mode == 2) {
                const int b = m >> 11, l = m & 2047, hh = n >> 7, d = n & 127;
                ((bf16*)out)[(((size_t)(b * NH_ + hh)) * L_ + l) * H_ + d] = __float2bfloat16(v);
            } else {
                const int b = m >> 11, q = m & 2047, g = n >> 7, hh = n & 127;
                ((float*)out)[(((size_t)(b * G_ + g)) * L_ + q) * H_ + hh] = v;
            }
        }
    }
}

// ---------------------------------------------------------------------------
// Flash attention v5: 256 thr = 4 waves = 4-way K-split of ONE 16-query tile.
// NO dynamically-indexed private arrays (v4's scratch-spill bug), no double
// buffering -- TLP (4 blocks/CU) hides L2 latency instead.
// Q,KV bf16 (BH,L,H); KVT bf16 (BH,H,L); O bf16 (B,L,NH*H). K==V.
// Grid: (BH=8, L/16=128) = 1024 blocks -> 4 blocks/CU, 16 waves/CU.
// ---------------------------------------------------------------------------
#define FTS 40      // Ps row stride (ushorts): 80 B, 16 B-aligned b128 reads

__global__ __launch_bounds__(256, 4)
void flash_attn_kernel(const bf16* __restrict__ Qb, const bf16* __restrict__ KVb,
                       const bf16* __restrict__ KVTb,
                       const float* __restrict__ mQ, const float* __restrict__ mK,
                       bf16* __restrict__ O)
{
    __shared__ __align__(16) char smem[30848];
    unsigned short* Ps = (unsigned short*)smem;             // 4*16*40*2 = 5120 B
    float* Ocomb = (float*)(smem + 5120);                   // 3*16*132*4 = 25344 B
    float* mcomb = (float*)(smem + 30464);                  // 192 B
    float* lcomb = (float*)(smem + 30656);                  // 192 B

    const int tid  = threadIdx.x;
    const int lane = tid & 63;
    const int wave = tid >> 6;        // K-split id 0..3
    const int quad = lane >> 4;
    const int l15  = lane & 15;
    const int bh = blockIdx.x, b = bh >> 1, h = bh & 1;
    const int q0 = blockIdx.y * 16;

    // Q fragments (row-major per-head)
    const bf16* qrow = Qb + ((size_t)bh * L_ + q0 + l15) * H_;
    bf16x8s qf[4];
    #pragma unroll
    for (int kc = 0; kc < 4; kc++)
        qf[kc] = *(const bf16x8s*)(qrow + kc * 32 + quad * 8);

    float qm[4];
    #pragma unroll
    for (int r = 0; r < 4; r++)
        qm[r] = (mQ == nullptr) ? 1.f : mQ[b * L_ + q0 + quad * 4 + r];

    float mo[4], li[4];
    f32x4 Oacc[8];
    #pragma unroll
    for (int r = 0; r < 4; r++) { mo[r] = -1e30f; li[r] = 0.f; }
    #pragma unroll
    for (int c = 0; c < 8; c++) Oacc[c] = (f32x4){0.f, 0.f, 0.f, 0.f};

    const float SCALE = 0.08838834764831845f;    // 1/sqrt(128)
    const bf16* kvb = KVb  + (size_t)bh * L_ * H_;
    const bf16* kvt = KVTb + (size_t)bh * H_ * L_;
    const float* mkb = mK + b * L_;
    unsigned short* pw = Ps + wave * 16 * FTS;

    const int ks0 = wave * 512;                  // this wave's key range

    for (int it = 0; it < 16; it++) {
        const int kbase = ks0 + it * 32;

        // ---- masks for this tile ----
        const float km0 = mkb[kbase + l15];
        const float km1 = mkb[kbase + 16 + l15];

        // ---- S = Q K^T (K-frags loaded inline, compile-time indices) ----
        f32x4 s0a = (f32x4){0.f,0.f,0.f,0.f}, s1a = (f32x4){0.f,0.f,0.f,0.f};
        #pragma unroll
        for (int kc = 0; kc < 4; kc++) {
            bf16x8s k0f = *(const bf16x8s*)(kvb + (size_t)(kbase + l15) * H_ + kc * 32 + quad * 8);
            bf16x8s k1f = *(const bf16x8s*)(kvb + (size_t)(kbase + 16 + l15) * H_ + kc * 32 + quad * 8);
            s0a = __builtin_amdgcn_mfma_f32_16x16x32_bf16(qf[kc], k0f, s0a, 0, 0, 0);
            s1a = __builtin_amdgcn_mfma_f32_16x16x32_bf16(qf[kc], k1f, s1a, 0, 0, 0);
        }

        // ---- V^T fragments (issued before softmax; latency hidden under it) ----
        bf16x8s vf0 = *(const bf16x8s*)(kvt + (size_t)(0 * 16 + l15) * L_ + kbase + quad * 8);
        bf16x8s vf1 = *(const bf16x8s*)(kvt + (size_t)(1 * 16 + l15) * L_ + kbase + quad * 8);
        bf16x8s vf2 = *(const bf16x8s*)(kvt + (size_t)(2 * 16 + l15) * L_ + kbase + quad * 8);
        bf16x8s vf3 = *(const bf16x8s*)(kvt + (size_t)(3 * 16 + l15) * L_ + kbase + quad * 8);

        // ---- mask + online softmax ----
        float s0[4], s1[4], mx[4];
        #pragma unroll
        for (int r = 0; r < 4; r++) {
            s0[r] = (km0 != 0.f && qm[r] != 0.f) ? s0a[r] * SCALE : -1000000.f;
            s1[r] = (km1 != 0.f && qm[r] != 0.f) ? s1a[r] * SCALE : -1000000.f;
            mx[r] = fmaxf(s0[r], s1[r]);
        }
        #pragma unroll
        for (int off = 1; off < 16; off <<= 1)
            #pragma unroll
            for (int r = 0; r < 4; r++) mx[r] = fmaxf(mx[r], __shfl_xor(mx[r], off));

        float p0[4], p1[4], rs[4], al[4];
        #pragma unroll
        for (int r = 0; r < 4; r++) {
            const float mn = fmaxf(mo[r], mx[r]);
            al[r] = __expf(mo[r] - mn);
            mo[r] = mn;
            p0[r] = __expf(s0[r] - mn);
            p1[r] = __expf(s1[r] - mn);
            rs[r] = p0[r] + p1[r];
        }
        #pragma unroll
        for (int off = 1; off < 16; off <<= 1)
            #pragma unroll
            for (int r = 0; r < 4; r++) rs[r] += __shfl_xor(rs[r], off);
        #pragma unroll
        for (int r = 0; r < 4; r++) li[r] = li[r] * al[r] + rs[r];
        #pragma unroll
        for (int c = 0; c < 8; c++)
            #pragma unroll
            for (int r = 0; r < 4; r++) Oacc[c][r] *= al[r];

        // ---- P -> LDS (wave-private, no barrier) -> A-frag ----
        #pragma unroll
        for (int r = 0; r < 4; r++) {
            pw[(quad * 4 + r) * FTS + l15]      = f2bf_bits(p0[r]);
            pw[(quad * 4 + r) * FTS + 16 + l15] = f2bf_bits(p1[r]);
        }
        bf16x8s pf = *(bf16x8s*)(&pw[l15 * FTS + quad * 8]);

        // ---- O += P V (first half with preloaded vf, second half inline) ----
        Oacc[0] = __builtin_amdgcn_mfma_f32_16x16x32_bf16(pf, vf0, Oacc[0], 0, 0, 0);
        Oacc[1] = __builtin_amdgcn_mfma_f32_16x16x32_bf16(pf, vf1, Oacc[1], 0, 0, 0);
        Oacc[2] = __builtin_amdgcn_mfma_f32_16x16x32_bf16(pf, vf2, Oacc[2], 0, 0, 0);
        Oacc[3] = __builtin_amdgcn_mfma_f32_16x16x32_bf16(pf, vf3, Oacc[3], 0, 0, 0);
        #pragma unroll
        for (int c = 4; c < 8; c++) {
            bf16x8s vfx = *(const bf16x8s*)(kvt + (size_t)(c * 16 + l15) * L_ + kbase + quad * 8);
            Oacc[c] = __builtin_amdgcn_mfma_f32_16x16x32_bf16(pf, vfx, Oacc[c], 0, 0, 0);
        }
    }

    // ---- 4-way K-split combine ----
    if (wave > 0) {
        const int s = wave - 1;
        #pragma unroll
        for (int c = 0; c < 8; c++)
            #pragma unroll
            for (int r = 0; r < 4; r++)
                Ocomb[(size_t)(s * 16 + quad * 4 + r) * 132 + c * 16 + l15] = Oacc[c][r];
        if (l15 == 0) {
            #pragma unroll
            for (int r = 0; r < 4; r++) {
                mcomb[s * 16 + quad * 4 + r] = mo[r];
                lcomb[s * 16 + quad * 4 + r] = li[r];
            }
        }
    }
    __syncthreads();
    if (wave == 0) {
        float ms[3][4], ls[3][4], M[4];
        #pragma unroll
        for (int r = 0; r < 4; r++) M[r] = mo[r];
        #pragma unroll
        for (int s = 0; s < 3; s++)
            #pragma unroll
            for (int r = 0; r < 4; r++) {
                ms[s][r] = mcomb[s * 16 + quad * 4 + r];
                ls[s][r] = lcomb[s * 16 + quad * 4 + r];
                M[r] = fmaxf(M[r], ms[s][r]);
            }
        float a0[4];
        #pragma unroll
        for (int r = 0; r < 4; r++) {
            a0[r] = __expf(mo[r] - M[r]);
            li[r] *= a0[r];
        }
        #pragma unroll
        for (int c = 0; c < 8; c++)
            #pragma unroll
            for (int r = 0; r < 4; r++) Oacc[c][r] *= a0[r];
        #pragma unroll
        for (int s = 0; s < 3; s++) {
            float as[4];
            #pragma unroll
            for (int r = 0; r < 4; r++) {
                as[r] = __expf(ms[s][r] - M[r]);
                li[r] += as[r] * ls[s][r];
            }
            #pragma unroll
            for (int c = 0; c < 8; c++)
                #pragma unroll
                for (int r = 0; r < 4; r++)
                    Oacc[c][r] += as[r] *
                        Ocomb[(size_t)(s * 16 + quad * 4 + r) * 132 + c * 16 + l15];
        }
        bf16* orow = O + ((size_t)b * L_ + q0) * (NH_ * H_) + h * H_;
        #pragma unroll
        for (int r = 0; r < 4; r++) {
            const float inv = 1.f / li[r];
            #pragma unroll
            for (int c = 0; c < 8; c++)
                orow[(size_t)(quad * 4 + r) * (NH_ * H_) + c * 16 + l15] =
                    __float2bfloat16(Oacc[c][r] * inv);
        }
    }
}

// ---------------------------------------------------------------------------
// qmw builder: mix_wt(10x128) @ ww_q(128x256) + b -> bf16 per-head (2,16,128)
// ---------------------------------------------------------------------------
__global__ __launch_bounds__(256)
void qmwb_kernel(const float* __restrict__ mixwt, const float* __restrict__ W,
                 const float* __restrict__ bias, bf16* __restrict__ qmwb)
{
    const int g = blockIdx.x;          // 0..15
    const int c = threadIdx.x;         // 0..255
    const int h = c >> 7, d = c & 127;
    if (g >= G_) { qmwb[((size_t)h * 16 + g) * 128 + d] = __float2bfloat16(0.f); return; }
    __shared__ float xr[128];
    if (c < 128) xr[c] = mixwt[g * 128 + c];
    __syncthreads();
    float acc = bias[c];
    #pragma unroll 8
    for (int i = 0; i < 128; i++)
        acc += xr[i] * W[i * 256 + c];
    qmwb[((size_t)h * 16 + g) * 128 + d] = __float2bfloat16(acc);
}

// ---------------------------------------------------------------------------
// mw partial attention: 16-way K-split. grid (16, NH, B), 256 threads.
// ---------------------------------------------------------------------------
__global__ __launch_bounds__(256)
void mwpartial_kernel(const bf16* __restrict__ qmwb, const bf16* __restrict__ kvmw,
                      const float* __restrict__ mK,
                      float* __restrict__ mwO, float* __restrict__ mwM,
                      float* __restrict__ mwL)
{
    __shared__ __align__(16) unsigned short Ks[128 * 136];
    __shared__ float Qs[10 * 128];
    __shared__ float sc[10 * 128];
    __shared__ float mst[10], lst[10];

    const int tid = threadIdx.x;
    const int split = blockIdx.x, h = blockIdx.y, b = blockIdx.z;
    const int kbase = split * 128;
    const float SCALE = 0.08838834764831845f;

    for (int idx = tid; idx < 1280; idx += 256)
        Qs[idx] = __bfloat162float(qmwb[((size_t)h * 16 + (idx >> 7)) * 128 + (idx & 127)]);
    {
        const int rr = tid >> 1, half = tid & 1;
        const bf16* src = kvmw + (((size_t)(b * NH_ + h)) * L_ + kbase + rr) * H_ + half * 64;
        #pragma unroll
        for (int i = 0; i < 8; i++)
            *(uint4*)(&Ks[rr * 136 + half * 64 + i * 8]) = *(const uint4*)(src + i * 8);
    }
    __syncthreads();

    {
        const int j = tid & 127, qh = tid >> 7;
        float acc[5] = {0.f, 0.f, 0.f, 0.f, 0.f};
        for (int dc = 0; dc < 128; dc += 8) {
            bf16x8s kv = *(bf16x8s*)(&Ks[j * 136 + dc]);
            float kf[8];
            #pragma unroll
            for (int e = 0; e < 8; e++) kf[e] = us2f(((unsigned short*)&kv)[e]);
            #pragma unroll
            for (int qq = 0; qq < 5; qq++) {
                const float* Qrow = &Qs[(qh * 5 + qq) * 128 + dc];
                #pragma unroll
                for (int e = 0; e < 8; e++) acc[qq] += Qrow[e] * kf[e];
            }
        }
        const bool kz = (mK[b * L_ + kbase + j] == 0.f);
        #pragma unroll
        for (int qq = 0; qq < 5; qq++)
            sc[(qh * 5 + qq) * 128 + j] = kz ? -1000000.f : acc[qq] * SCALE;
    }
    __syncthreads();
    if (tid < 160) {
        const int q = tid >> 4, t16 = tid & 15;
        float m = -3.4e38f;
        for (int jj = t16; jj < 128; jj += 16) m = fmaxf(m, sc[q * 128 + jj]);
        #pragma unroll
        for (int off = 1; off < 16; off <<= 1) m = fmaxf(m, __shfl_xor(m, off));
        if (t16 == 0) mst[q] = m;
    }
    __syncthreads();
    {
        const int j = tid & 127, qh = tid >> 7;
        #pragma unroll
        for (int qq = 0; qq < 5; qq++) {
            const int idx = (qh * 5 + qq) * 128 + j;
            sc[idx] = __expf(sc[idx] - mst[qh * 5 + qq]);
        }
    }
    __syncthreads();
    if (tid < 160) {
        const int q = tid >> 4, t16 = tid & 15;
        float s = 0.f;
        for (int jj = t16; jj < 128; jj += 16) s += sc[q * 128 + jj];
        #pragma unroll
        for (int off = 1; off < 16; off <<= 1) s += __shfl_xor(s, off);
        if (t16 == 0) lst[q] = s;
    }
    __syncthreads();
    {
        const int d = tid & 127, qh = tid >> 7;
        float acc[5] = {0.f, 0.f, 0.f, 0.f, 0.f};
        for (int jj = 0; jj < 128; jj++) {
            const float v = us2f(Ks[jj * 136 + d]);
            #pragma unroll
            for (int qq = 0; qq < 5; qq++)
                acc[qq] += sc[(qh * 5 + qq) * 128 + jj] * v;
        }
        const size_t base = ((size_t)(b * NH_ + h) * 16 + split) * 10;
        #pragma unroll
        for (int qq = 0; qq < 5; qq++)
            mwO[(base + qh * 5 + qq) * 128 + d] = acc[qq];
    }
    if (tid < 10) {
        const size_t base = ((size_t)(b * NH_ + h) * 16 + split) * 10;
        mwM[base + tid] = mst[tid];
        mwL[base + tid] = lst[tid];
    }
}

// mw combine: merge 16 K-splits -> mwat (B*10, 256) fp32. grid 40 x 256
__global__ __launch_bounds__(256)
void mwcombine_kernel(const float* __restrict__ mwO, const float* __restrict__ mwM,
                      const float* __restrict__ mwL, float* __restrict__ mwat)
{
    const int bg = blockIdx.x;
    const int b = bg / G_, q = bg % G_;
    const int h = threadIdx.x >> 7, d = threadIdx.x & 127;
    const size_t hb = (size_t)(b * NH_ + h) * 16;
    float M = -3.4e38f;
    for (int s = 0; s < 16; s++) M = fmaxf(M, mwM[(hb + s) * 10 + q]);
    float l = 0.f, o = 0.f;
    for (int s = 0; s < 16; s++) {
        const float a = __expf(mwM[(hb + s) * 10 + q] - M);
        l += a * mwL[(hb + s) * 10 + q];
        o += a * mwO[((hb + s) * 10 + q) * 128 + d];
    }
    mwat[(size_t)bg * 256 + h * 128 + d] = o / l;
}

// mw output projection: mw_ = mix_wt[g] + attn@ww_o + ww_ob ; grid B*G x 128
__global__ __launch_bounds__(128)
void mwproj_kernel(const float* __restrict__ A, const float* __restrict__ mixwt,
                   const float* __restrict__ W, const float* __restrict__ bias,
                   float* __restrict__ Y)
{
    const int bg  = blockIdx.x;
    const int g   = bg % G_;
    const int tid = threadIdx.x;
    __shared__ float ar[256];
    ar[tid]       = A[(size_t)bg * 256 + tid];
    ar[tid + 128] = A[(size_t)bg * 256 + tid + 128];
    __syncthreads();
    float acc = mixwt[g * 128 + tid] + bias[tid];
    #pragma unroll 8
    for (int i = 0; i < 256; i++)
        acc += ar[i] * W[i * 128 + tid];
    Y[(size_t)bg * 128 + tid] = acc;
}

__global__ __launch_bounds__(64)
void mwfinal_kernel(const float* __restrict__ MW, const float* __restrict__ wmix,
                    const float* __restrict__ bmix, float* __restrict__ out)
{
    const int b = blockIdx.x;
    const int g = threadIdx.x;
    __shared__ float z[16];
    if (g < G_) {
        float acc = bmix[0];
        for (int i = 0; i < 128; i++)
            acc += MW[((size_t)b * G_ + g) * 128 + i] * wmix[i];
        z[g] = acc;
    }
    __syncthreads();
    if (g == 0) {
        float mx = -3.4e38f;
        for (int i = 0; i < G_; i++) mx = fmaxf(mx, z[i]);
        float e[G_]; float s = 0.f;
        for (int i = 0; i < G_; i++) { e[i] = __expf(z[i] - mx); s += e[i]; }
        for (int i = 0; i < G_; i++) out[b * G_ + i] = e[i] / s;
    }
}

// ---------------------------------------------------------------------------
extern "C" void kernel_launch(void* const* d_in, const int* in_sizes, int n_in,
                              void* d_out, int out_size, void* d_ws, size_t ws_size,
                              hipStream_t stream)
{
    const float* obs    = (const float*)d_in[0];
    const float* mobs   = (const float*)d_in[1];
    const float* xq     = (const float*)d_in[2];
    const float* mq     = (const float*)d_in[3];
    const float* w_q0   = (const float*)d_in[4];
    const float* b_q0   = (const float*)d_in[5];
    const float* w_q1   = (const float*)d_in[6];
    const float* b_q1   = (const float*)d_in[7];
    const float* w_o0   = (const float*)d_in[8];
    const float* b_o0   = (const float*)d_in[9];
    const float* w_o1   = (const float*)d_in[10];
    const float* b_o1   = (const float*)d_in[11];
    const float* w_cobs = (const float*)d_in[12];
    const float* b_cobs = (const float*)d_in[13];
    const float* w_cq   = (const float*)d_in[14];
    const float* b_cq   = (const float*)d_in[15];
    const float* w_qp   = (const float*)d_in[16];
    const float* b_qp   = (const float*)d_in[17];
    const float* w_kp   = (const float*)d_in[18];
    const float* b_kp   = (const float*)d_in[19];
    const float* ws_q   = (const float*)d_in[20];
    const float* ws_qb  = (const float*)d_in[21];
    const float* ws_o   = (const float*)d_in[22];
    const float* ws_ob  = (const float*)d_in[23];
    const float* ww_q   = (const float*)d_in[24];
    const float* ww_qb  = (const float*)d_in[25];
    const float* ww_o   = (const float*)d_in[26];
    const float* ww_ob  = (const float*)d_in[27];
    const float* wc_q   = (const float*)d_in[28];
    const float* wc_qb  = (const float*)d_in[29];
    const float* wc_o   = (const float*)d_in[30];
    const float* wc_ob  = (const float*)d_in[31];
    const float* w_split= (const float*)d_in[32];
    const float* b_split= (const float*)d_in[33];
    const float* mix_wt = (const float*)d_in[34];
    const float* w_mix  = (const float*)d_in[35];
    const float* b_mix  = (const float*)d_in[36];

    float* out = (float*)d_out;
    char* ws  = (char*)d_ws;

    const size_t MB = (size_t)1 << 20;
    const size_t KB = (size_t)1 << 10;
    if (ws_size < 31 * MB) return;

    const int NROW = B_ * L_;          // 8192
    // layout (<=30 MB). qcb+kvcb and qe_bf+x_bf pairs MUST be contiguous.
    bf16* featq = (bf16*)(ws + 0);                 // 4 MB  -> kvbs, later qcb
    bf16* feato = (bf16*)(ws + 4 * MB);            // 4.5 MB -> later kvcb (at +4MB!)
    bf16* qe_bf = (bf16*)(ws + 8 * MB + 512 * KB); // 2 MB  \ contiguous pair
    bf16* x_bf  = (bf16*)(ws + 10 * MB + 512 * KB);// 2 MB  / for merged gemm
    bf16* oe_bf = (bf16*)(ws + 12 * MB + 512 * KB);// 2 MB
    bf16* abuf  = (bf16*)(ws + 14 * MB + 512 * KB);// 4 MB -> abuf2
    bf16* x2_bf = (bf16*)(ws + 18 * MB + 512 * KB);// 2 MB
    bf16* kvmw  = (bf16*)(ws + 20 * MB + 512 * KB);// 4 MB
    bf16* kvT   = (bf16*)(ws + 24 * MB + 512 * KB);// 4 MB (BH,H,L), self then cross
    char* wbase = ws + 28 * MB + 512 * KB;         // ~1.5 MB of weights/smalls
    bf16* wqpT  = (bf16*)(wbase + 0);              // 64 KB (128 x 256)
    bf16* wkpT  = (bf16*)(wbase + 64 * KB);        // 72 KB (128 x 288)
    bf16* wsqT  = (bf16*)(wbase + 136 * KB);       // 64 KB (256 x 128)
    bf16* wsoT  = (bf16*)(wbase + 200 * KB);       // 64 KB (128 x 256)
    bf16* wwqT  = (bf16*)(wbase + 264 * KB);       // 64 KB
    bf16* wcqT  = (bf16*)(wbase + 328 * KB);       // 64 KB
    bf16* wcoT  = (bf16*)(wbase + 392 * KB);       // 64 KB
    bf16* wsplT = (bf16*)(wbase + 456 * KB);       // 320 KB (1280 x 128)
    bf16* qmwb  = (bf16*)(wbase + 776 * KB);       // 8 KB (2,16,128)
    float* mwO  = (float*)(wbase + 784 * KB);      // 640 KB
    float* mwM  = (float*)(wbase + 1424 * KB);     // 5 KB
    float* mwL  = (float*)(wbase + 1432 * KB);     // 5 KB
    float* mwat = (float*)(wbase + 1440 * KB);     // 40 KB
    float* mw_  = (float*)(wbase + 1480 * KB);     // 20 KB
    bf16* kvbs  = featq;                           // self QKV (B,NH,L,H)
    bf16* qcb   = featq;                           // cross Q  (B,NH,L,H)
    bf16* kvcb  = (bf16*)(ws + 4 * MB);            // cross KV = qcb + 4MB
    bf16* abuf2 = abuf;

    // 0: all weight transposes in one launch
    WtArgs wa;
    wa.W[0]=w_qp;   wa.T[0]=wqpT;  wa.K[0]=256; wa.Kp[0]=256; wa.N[0]=128;
    wa.W[1]=w_kp;   wa.T[1]=wkpT;  wa.K[1]=257; wa.Kp[1]=288; wa.N[1]=128;
    wa.W[2]=ws_q;   wa.T[2]=wsqT;  wa.K[2]=128; wa.Kp[2]=128; wa.N[2]=256;
    wa.W[3]=ws_o;   wa.T[3]=wsoT;  wa.K[3]=256; wa.Kp[3]=256; wa.N[3]=128;
    wa.W[4]=ww_q;   wa.T[4]=wwqT;  wa.K[4]=128; wa.Kp[4]=128; wa.N[4]=256;
    wa.W[5]=wc_q;   wa.T[5]=wcqT;  wa.K[5]=128; wa.Kp[5]=128; wa.N[5]=256;
    wa.W[6]=wc_o;   wa.T[6]=wcoT;  wa.K[6]=256; wa.Kp[6]=256; wa.N[6]=128;
    wa.W[7]=w_split;wa.T[7]=wsplT; wa.K[7]=128; wa.Kp[7]=128; wa.N[7]=1280;
    wtrans_all_kernel<<<dim3(1280, 8), 288, 0, stream>>>(wa);

    // 1-2: featurize
    featq_kernel<<<NROW, 128, 0, stream>>>(xq, mq, w_q0, b_q0, w_q1, b_q1,
                                           w_cq, b_cq, featq);
    feato_kernel<<<NROW, 128, 0, stream>>>(obs, mobs, w_o0, b_o0, w_o1, b_o1,
                                           w_cobs, b_cobs, feato);
    // 3-4: embed projections (MFMA)
    gemm_kernel<<<dim3(NROW/32, 2), 128, 0, stream>>>(featq, wqpT, b_qp, nullptr,
                                                      qe_bf, 256, 128, 1, 0);
    gemm_kernel<<<dim3(NROW/32, 2), 128, 0, stream>>>(feato, wkpT, b_kp, nullptr,
                                                      oe_bf, 288, 128, 1, 0);
    // 5: self-attn shared q=k=v projection (per-head bf16) + transpose
    gemm_kernel<<<dim3(NROW/32, 4), 128, 0, stream>>>(oe_bf, wsqT, ws_qb, nullptr,
                                                      kvbs, 128, 256, 2, 0);
    kvtrans_kernel<<<dim3(L_/64, B_*NH_), 256, 0, stream>>>(kvbs, kvT);
    // 6: self attention (flash v5)
    flash_attn_kernel<<<dim3(B_*NH_, L_/16), 256, 0, stream>>>(kvbs, kvbs, kvT,
                                                               nullptr, mobs, abuf);
    // 7: x = relu(oe + attn @ ws_o + ws_ob)
    gemm_kernel<<<dim3(NROW/32, 2), 128, 0, stream>>>(abuf, wsoT, ws_ob, oe_bf,
                                                      x_bf, 256, 128, 1, 1);
    // 8-13: mixing-weights path
    qmwb_kernel<<<16, 256, 0, stream>>>(mix_wt, ww_q, ww_qb, qmwb);
    gemm_kernel<<<dim3(NROW/32, 4), 128, 0, stream>>>(x_bf, wwqT, ww_qb, nullptr,
                                                      kvmw, 128, 256, 2, 0);
    mwpartial_kernel<<<dim3(16, NH_, B_), 256, 0, stream>>>(qmwb, kvmw, mobs,
                                                            mwO, mwM, mwL);
    mwcombine_kernel<<<B_ * G_, 256, 0, stream>>>(mwO, mwM, mwL, mwat);
    mwproj_kernel<<<B_ * G_, 128, 0, stream>>>(mwat, mix_wt, ww_o, ww_ob, mw_);
    mwfinal_kernel<<<B_, 64, 0, stream>>>(mw_, w_mix, b_mix,
                                          out + (size_t)B_ * G_ * L_ * H_);
    // 14: merged cross projections: [qe_bf; x_bf](16384x128) @ wc_q -> [qcb; kvcb]
    gemm_kernel<<<dim3(2*NROW/32, 4), 128, 0, stream>>>(qe_bf, wcqT, wc_qb, nullptr,
                                                        qcb, 128, 256, 2, 0);
    kvtrans_kernel<<<dim3(L_/64, B_*NH_), 256, 0, stream>>>(kvcb, kvT);
    // 16: cross attention
    flash_attn_kernel<<<dim3(B_*NH_, L_/16), 256, 0, stream>>>(qcb, kvcb, kvT,
                                                               mq, mobs, abuf2);
    // 17: x2 = relu(qe + attn2 @ wc_o + wc_ob)
    gemm_kernel<<<dim3(NROW/32, 2), 128, 0, stream>>>(abuf2, wcoT, wc_ob, qe_bf,
                                                      x2_bf, 256, 128, 1, 1);
    // 18: split + transpose store (MFMA)
    gemm_kernel<<<dim3(NROW/32, 20), 128, 0, stream>>>(x2_bf, wsplT, b_split, nullptr,
                                                       out, 128, 1280, 3, 0);

    (void)in_sizes; (void)n_in; (void)out_size;
}